// Round 2
// baseline (1242.298 us; speedup 1.0000x reference)
//
#include <hip/hip_runtime.h>
#include <hip/hip_bf16.h>
#include <stdint.h>

// LightningIndexer: importance[b,q,k] = sum_h w[b,q,h] * relu( qh[b,q,:] . kv[b,k,:] )
// B=2, T=4096, C=2048, H=16, D=32.
// Pipeline: (1) cast x + pack W -> bf16, (2) MFMA GEMM projections, (3) fused score kernel.
// Workspace use: ~47.2 MB (xb 32MiB | Wp 2.5MiB | qkw 10MiB | w_f32 0.5MiB).

typedef __attribute__((ext_vector_type(8))) short bf16x8;
typedef __attribute__((ext_vector_type(4))) float f32x4;
typedef __attribute__((ext_vector_type(2))) __fp16 f16x2;   // clang builtin half2 type

#define NPAD 640   // 512 q cols + 32 k cols + 16 w cols + 80 zero pad (5 tiles of 128)
#define KCOL 512
#define WCOL 544

__device__ __forceinline__ unsigned short f2bf(float f) {
  union { float f; unsigned u; } c; c.f = f;
  unsigned u = c.u;
  u += 0x7FFFu + ((u >> 16) & 1u);   // round-to-nearest-even
  return (unsigned short)(u >> 16);
}

__device__ __forceinline__ f16x2 u32_to_h2(unsigned u) {
  union { unsigned u; f16x2 h; } c; c.u = u; return c.h;
}
__device__ __forceinline__ unsigned h2_to_u32(f16x2 h) {
  union { unsigned u; f16x2 h; } c; c.h = h; return c.u;
}

__device__ __forceinline__ void async_copy16(void* lds, const void* g) {
  __builtin_amdgcn_global_load_lds(
      (const __attribute__((address_space(1))) unsigned*)g,
      (__attribute__((address_space(3))) unsigned*)lds, 16, 0, 0);
}

// ---------------- kernel 1: cast x to bf16, pack Wq/Wk/Ww (+zero pad) ----------------
__global__ __launch_bounds__(256) void pack_kernel(
    const float* __restrict__ x, const float* __restrict__ Wq,
    const float* __restrict__ Wk, const float* __restrict__ Ww,
    unsigned short* __restrict__ xb, unsigned short* __restrict__ Wp) {
  const int64_t NX4 = 16777216 / 4;          // x float4 count
  int64_t i = (int64_t)blockIdx.x * 256 + threadIdx.x;
  if (i < NX4) {
    float4 v = ((const float4*)x)[i];
    ushort4 o;
    o.x = f2bf(v.x); o.y = f2bf(v.y); o.z = f2bf(v.z); o.w = f2bf(v.w);
    ((ushort4*)xb)[i] = o;
  } else {
    int p = (int)(i - NX4);                  // 0 .. 640*2048/4-1 = 327679
    int row = p >> 9;                        // 512 float4 per 2048-col row
    int col = (p & 511) << 2;
    float4 v = make_float4(0.f, 0.f, 0.f, 0.f);
    if (row < 512)      v = *(const float4*)(Wq + (int64_t)row * 2048 + col);
    else if (row < 544) v = *(const float4*)(Wk + (int64_t)(row - 512) * 2048 + col);
    else if (row < 560) v = *(const float4*)(Ww + (int64_t)(row - 544) * 2048 + col);
    ushort4 o;
    o.x = f2bf(v.x); o.y = f2bf(v.y); o.z = f2bf(v.z); o.w = f2bf(v.w);
    ((ushort4*)Wp)[p] = o;
  }
}

// ---------------- kernel 2: qkw = x @ Wp^T  (8192 x 640 x 2048, bf16 MFMA) ----------------
__global__ __launch_bounds__(256) void gemm_proj(
    const unsigned short* __restrict__ xb, const unsigned short* __restrict__ Wp,
    unsigned short* __restrict__ qkwb, float* __restrict__ wf) {
  __shared__ short lds_a[128 * 32];
  __shared__ short lds_b[128 * 32];
  const int tid = threadIdx.x;
  const int lane = tid & 63;
  const int l15 = lane & 15, quad = lane >> 4;
  const int wave = tid >> 6;
  const int wm = wave >> 1, wn = wave & 1;
  const int m0 = blockIdx.y * 128, n0 = blockIdx.x * 128;

  const int c0 = tid, c1 = tid + 256;        // 16B chunk ids, 512 per tile
  const unsigned short* ga0 = xb + (int64_t)(m0 + (c0 >> 2)) * 2048 + (c0 & 3) * 8;
  const unsigned short* ga1 = xb + (int64_t)(m0 + (c1 >> 2)) * 2048 + (c1 & 3) * 8;
  const unsigned short* gb0 = Wp + (int64_t)(n0 + (c0 >> 2)) * 2048 + (c0 & 3) * 8;
  const unsigned short* gb1 = Wp + (int64_t)(n0 + (c1 >> 2)) * 2048 + (c1 & 3) * 8;

  f32x4 acc[4][4] = {};

  for (int kt = 0; kt < 64; ++kt) {
    const int ko = kt * 32;
    async_copy16(&lds_a[c0 * 8], ga0 + ko);
    async_copy16(&lds_a[c1 * 8], ga1 + ko);
    async_copy16(&lds_b[c0 * 8], gb0 + ko);
    async_copy16(&lds_b[c1 * 8], gb1 + ko);
    __syncthreads();
    bf16x8 af[4], bfr[4];
#pragma unroll
    for (int i = 0; i < 4; ++i)
      af[i] = *(const bf16x8*)&lds_a[(wm * 64 + i * 16 + l15) * 32 + quad * 8];
#pragma unroll
    for (int j = 0; j < 4; ++j)
      bfr[j] = *(const bf16x8*)&lds_b[(wn * 64 + j * 16 + l15) * 32 + quad * 8];
#pragma unroll
    for (int i = 0; i < 4; ++i)
#pragma unroll
      for (int j = 0; j < 4; ++j)
        acc[i][j] = __builtin_amdgcn_mfma_f32_16x16x32_bf16(af[i], bfr[j], acc[i][j], 0, 0, 0);
    __syncthreads();
  }

#pragma unroll
  for (int i = 0; i < 4; ++i)
#pragma unroll
    for (int j = 0; j < 4; ++j)
#pragma unroll
      for (int r = 0; r < 4; ++r) {
        int m = m0 + wm * 64 + i * 16 + quad * 4 + r;
        int n = n0 + wn * 64 + j * 16 + l15;
        float v = acc[i][j][r];
        qkwb[(int64_t)m * NPAD + n] = f2bf(v);
        if (n >= WCOL && n < WCOL + 16) wf[m * 16 + (n - WCOL)] = v;  // w kept fp32
      }
}

// ---------------- kernel 3: fused scores ----------------
// Block: 128 k x 128 q tile (transposed compute: D row = k, D col = q).
// Heads processed in PAIRS: per element-pair the relu/weight/accumulate is
// cvt_pkrtz + v_pk_max_f16 + v_dot2_f32_f16 = 3 VALU ops for 2 head-terms
// (1.5 ops/elem-head vs ~9 in the previous f32 epilogue).
__global__ __launch_bounds__(256, 2) void scores_kernel(
    const unsigned short* __restrict__ qkwb, const float* __restrict__ wf,
    float* __restrict__ out) {
  const int kt = blockIdx.x, qt = blockIdx.y, b = blockIdx.z;
  const int tid = threadIdx.x;
  const int lane = tid & 63;
  const int l15 = lane & 15, quad = lane >> 4;
  const int wave = tid >> 6;
  const int wk = wave & 1, wq = wave >> 1;

  __shared__ unsigned w2[8][132];            // packed half2 {w[q,2hp], w[q,2hp+1]}

  const int qrow0 = b * 4096 + qt * 128;
  const int krow0 = b * 4096 + kt * 128;

  // stage w tile: 128 rows x 16 heads fp32 -> half2 pairs
  {
    const float4* ws = (const float4*)(wf + (int64_t)qrow0 * 16);
#pragma unroll
    for (int r = 0; r < 2; ++r) {
      int f = tid * 2 + r;                   // 0..511 float4s
      float4 v = ws[f];
      int row = f >> 2, hb = (f & 3) * 4;    // heads hb..hb+3 (hb in {0,4,8,12})
      f16x2 p01, p23;
      p01.x = (__fp16)v.x; p01.y = (__fp16)v.y;
      p23.x = (__fp16)v.z; p23.y = (__fp16)v.w;
      w2[(hb >> 1) + 0][row] = h2_to_u32(p01);
      w2[(hb >> 1) + 1][row] = h2_to_u32(p23);
    }
  }

  // K fragments: shared across all 16 heads, kept in registers
  bf16x8 ka[4];
#pragma unroll
  for (int i = 0; i < 4; ++i) {
    int kk = krow0 + wk * 64 + i * 16 + l15;
    ka[i] = *(const bf16x8*)&qkwb[(int64_t)kk * NPAD + KCOL + quad * 8];
  }

  const unsigned short* qbase =
      qkwb + (int64_t)(qrow0 + wq * 64 + l15) * NPAD + quad * 8;

  f32x4 acc[4][4] = {};
  __syncthreads();

  // hoist all packed weights into registers: wpk[hp][j] = {w[q,2hp], w[q,2hp+1]}
  f16x2 wpk[8][4];
#pragma unroll
  for (int hp = 0; hp < 8; ++hp)
#pragma unroll
    for (int j = 0; j < 4; ++j)
      wpk[hp][j] = u32_to_h2(w2[hp][wq * 64 + j * 16 + l15]);

  const f16x2 hz = u32_to_h2(0u);
  const f32x4 z = {0.f, 0.f, 0.f, 0.f};

  // ping-pong q fragments across head pairs (fully unrolled -> static indices)
  bf16x8 qa[2][4], qb[2][4];
#pragma unroll
  for (int j = 0; j < 4; ++j) {
    qa[0][j] = *(const bf16x8*)&qbase[(int64_t)j * 16 * NPAD + 0 * 32];
    qb[0][j] = *(const bf16x8*)&qbase[(int64_t)j * 16 * NPAD + 1 * 32];
  }

#pragma unroll
  for (int hp = 0; hp < 8; ++hp) {
    const int cur = hp & 1, nxt = cur ^ 1;
    if (hp < 7) {
#pragma unroll
      for (int j = 0; j < 4; ++j) {
        qa[nxt][j] = *(const bf16x8*)&qbase[(int64_t)j * 16 * NPAD + (2 * hp + 2) * 32];
        qb[nxt][j] = *(const bf16x8*)&qbase[(int64_t)j * 16 * NPAD + (2 * hp + 3) * 32];
      }
    }
#pragma unroll
    for (int i = 0; i < 4; ++i)
#pragma unroll
      for (int j = 0; j < 4; ++j) {
        f32x4 t0 = __builtin_amdgcn_mfma_f32_16x16x32_bf16(ka[i], qa[cur][j], z, 0, 0, 0);
        f32x4 t1 = __builtin_amdgcn_mfma_f32_16x16x32_bf16(ka[i], qb[cur][j], z, 0, 0, 0);
#pragma unroll
        for (int r = 0; r < 4; ++r) {
          f16x2 p = __builtin_amdgcn_cvt_pkrtz(t0[r], t1[r]);   // {s_h0, s_h1} f16
          p = __builtin_elementwise_max(p, hz);                  // relu both halves
          acc[i][j][r] = __builtin_amdgcn_fdot2(p, wpk[hp][j], acc[i][j][r], false);
        }
      }
  }

  // store: per (i,j) one dwordx4 along k
#pragma unroll
  for (int i = 0; i < 4; ++i)
#pragma unroll
    for (int j = 0; j < 4; ++j) {
      int q = qt * 128 + wq * 64 + j * 16 + l15;
      int k = kt * 128 + wk * 64 + i * 16 + quad * 4;
      float4 v = make_float4(acc[i][j][0], acc[i][j][1], acc[i][j][2], acc[i][j][3]);
      *(float4*)&out[((int64_t)b * 4096 + q) * 4096 + k] = v;
    }
}

extern "C" void kernel_launch(void* const* d_in, const int* in_sizes, int n_in,
                              void* d_out, int out_size, void* d_ws, size_t ws_size,
                              hipStream_t stream) {
  const float* x  = (const float*)d_in[0];
  const float* Wq = (const float*)d_in[1];
  const float* Wk = (const float*)d_in[2];
  const float* Ww = (const float*)d_in[3];
  float* out = (float*)d_out;

  char* ws = (char*)d_ws;
  unsigned short* xb   = (unsigned short*)ws;                 // 8192x2048 bf16 = 33,554,432 B
  unsigned short* Wp   = (unsigned short*)(ws + 33554432);    // 640x2048 bf16  =  2,621,440 B
  unsigned short* qkwb = (unsigned short*)(ws + 36175872);    // 8192x640 bf16  = 10,485,760 B
  float*          wf   = (float*)(ws + 46661632);             // 8192x16 fp32   =    524,288 B

  pack_kernel<<<17664, 256, 0, stream>>>(x, Wq, Wk, Ww, xb, Wp);
  gemm_proj<<<dim3(5, 64), 256, 0, stream>>>(xb, Wp, qkwb, wf);
  scores_kernel<<<dim3(32, 32, 2), 256, 0, stream>>>(qkwb, wf, out);
}

// Round 3
// 311.189 us; speedup vs baseline: 3.9921x; 3.9921x over previous
//
#include <hip/hip_runtime.h>
#include <hip/hip_bf16.h>
#include <stdint.h>

// LightningIndexer: importance[b,q,k] = sum_h w[b,q,h] * relu( qh[b,q,:] . kv[b,k,:] )
// B=2, T=4096, C=2048, H=16, D=32.
// Pipeline: (1) cast x + pack W -> bf16, (2) MFMA GEMM projections, (3) fused score kernel.
// Workspace use: ~47.2 MB (xb 32MiB | Wp 2.5MiB | qkw 10MiB | w_f32 0.5MiB).

typedef __attribute__((ext_vector_type(8))) short bf16x8;
typedef __attribute__((ext_vector_type(4))) float f32x4;
typedef __attribute__((ext_vector_type(2))) __fp16 f16x2;   // clang builtin half2 type

#define NPAD 640   // 512 q cols + 32 k cols + 16 w cols + 80 zero pad (5 tiles of 128)
#define KCOL 512
#define WCOL 544

__device__ __forceinline__ unsigned short f2bf(float f) {
  union { float f; unsigned u; } c; c.f = f;
  unsigned u = c.u;
  u += 0x7FFFu + ((u >> 16) & 1u);   // round-to-nearest-even
  return (unsigned short)(u >> 16);
}

__device__ __forceinline__ f16x2 u32_to_h2(unsigned u) {
  union { unsigned u; f16x2 h; } c; c.u = u; return c.h;
}
__device__ __forceinline__ unsigned h2_to_u32(f16x2 h) {
  union { unsigned u; f16x2 h; } c; c.h = h; return c.u;
}

__device__ __forceinline__ void async_copy16(void* lds, const void* g) {
  __builtin_amdgcn_global_load_lds(
      (const __attribute__((address_space(1))) unsigned*)g,
      (__attribute__((address_space(3))) unsigned*)lds, 16, 0, 0);
}

// ---------------- kernel 1: cast x to bf16, pack Wq/Wk/Ww (+zero pad) ----------------
__global__ __launch_bounds__(256) void pack_kernel(
    const float* __restrict__ x, const float* __restrict__ Wq,
    const float* __restrict__ Wk, const float* __restrict__ Ww,
    unsigned short* __restrict__ xb, unsigned short* __restrict__ Wp) {
  const int64_t NX4 = 16777216 / 4;          // x float4 count
  int64_t i = (int64_t)blockIdx.x * 256 + threadIdx.x;
  if (i < NX4) {
    float4 v = ((const float4*)x)[i];
    ushort4 o;
    o.x = f2bf(v.x); o.y = f2bf(v.y); o.z = f2bf(v.z); o.w = f2bf(v.w);
    ((ushort4*)xb)[i] = o;
  } else {
    int p = (int)(i - NX4);                  // 0 .. 640*2048/4-1 = 327679
    int row = p >> 9;                        // 512 float4 per 2048-col row
    int col = (p & 511) << 2;
    float4 v = make_float4(0.f, 0.f, 0.f, 0.f);
    if (row < 512)      v = *(const float4*)(Wq + (int64_t)row * 2048 + col);
    else if (row < 544) v = *(const float4*)(Wk + (int64_t)(row - 512) * 2048 + col);
    else if (row < 560) v = *(const float4*)(Ww + (int64_t)(row - 544) * 2048 + col);
    ushort4 o;
    o.x = f2bf(v.x); o.y = f2bf(v.y); o.z = f2bf(v.z); o.w = f2bf(v.w);
    ((ushort4*)Wp)[p] = o;
  }
}

// ---------------- kernel 2: qkw = x @ Wp^T  (8192 x 640 x 2048, bf16 MFMA) ----------------
__global__ __launch_bounds__(256) void gemm_proj(
    const unsigned short* __restrict__ xb, const unsigned short* __restrict__ Wp,
    unsigned short* __restrict__ qkwb, float* __restrict__ wf) {
  __shared__ short lds_a[128 * 32];
  __shared__ short lds_b[128 * 32];
  const int tid = threadIdx.x;
  const int lane = tid & 63;
  const int l15 = lane & 15, quad = lane >> 4;
  const int wave = tid >> 6;
  const int wm = wave >> 1, wn = wave & 1;
  const int m0 = blockIdx.y * 128, n0 = blockIdx.x * 128;

  const int c0 = tid, c1 = tid + 256;        // 16B chunk ids, 512 per tile
  const unsigned short* ga0 = xb + (int64_t)(m0 + (c0 >> 2)) * 2048 + (c0 & 3) * 8;
  const unsigned short* ga1 = xb + (int64_t)(m0 + (c1 >> 2)) * 2048 + (c1 & 3) * 8;
  const unsigned short* gb0 = Wp + (int64_t)(n0 + (c0 >> 2)) * 2048 + (c0 & 3) * 8;
  const unsigned short* gb1 = Wp + (int64_t)(n0 + (c1 >> 2)) * 2048 + (c1 & 3) * 8;

  f32x4 acc[4][4] = {};

  for (int kt = 0; kt < 64; ++kt) {
    const int ko = kt * 32;
    async_copy16(&lds_a[c0 * 8], ga0 + ko);
    async_copy16(&lds_a[c1 * 8], ga1 + ko);
    async_copy16(&lds_b[c0 * 8], gb0 + ko);
    async_copy16(&lds_b[c1 * 8], gb1 + ko);
    __syncthreads();
    bf16x8 af[4], bfr[4];
#pragma unroll
    for (int i = 0; i < 4; ++i)
      af[i] = *(const bf16x8*)&lds_a[(wm * 64 + i * 16 + l15) * 32 + quad * 8];
#pragma unroll
    for (int j = 0; j < 4; ++j)
      bfr[j] = *(const bf16x8*)&lds_b[(wn * 64 + j * 16 + l15) * 32 + quad * 8];
#pragma unroll
    for (int i = 0; i < 4; ++i)
#pragma unroll
      for (int j = 0; j < 4; ++j)
        acc[i][j] = __builtin_amdgcn_mfma_f32_16x16x32_bf16(af[i], bfr[j], acc[i][j], 0, 0, 0);
    __syncthreads();
  }

#pragma unroll
  for (int i = 0; i < 4; ++i)
#pragma unroll
    for (int j = 0; j < 4; ++j)
#pragma unroll
      for (int r = 0; r < 4; ++r) {
        int m = m0 + wm * 64 + i * 16 + quad * 4 + r;
        int n = n0 + wn * 64 + j * 16 + l15;
        float v = acc[i][j][r];
        qkwb[(int64_t)m * NPAD + n] = f2bf(v);
        if (n >= WCOL && n < WCOL + 16) wf[m * 16 + (n - WCOL)] = v;  // w kept fp32
      }
}

// ---------------- kernel 3: fused scores ----------------
// Block: 128 k x 128 q tile (transposed compute: D row = k, D col = q).
// Heads processed in PAIRS: per element-pair the relu/weight/accumulate is
// cvt_pkrtz + v_pk_max_f16 + v_dot2_f32_f16 = 3 VALU ops for 2 head-terms.
// NOTE: no cross-iteration register arrays (rule #20 — the ping-pong version
// spilled to scratch: 1.56 GB WRITE_SIZE). q fragments are loaded fresh per
// head-pair into loop-local, statically-indexed arrays.
__global__ __launch_bounds__(256) void scores_kernel(
    const unsigned short* __restrict__ qkwb, const float* __restrict__ wf,
    float* __restrict__ out) {
  const int kt = blockIdx.x, qt = blockIdx.y, b = blockIdx.z;
  const int tid = threadIdx.x;
  const int lane = tid & 63;
  const int l15 = lane & 15, quad = lane >> 4;
  const int wave = tid >> 6;
  const int wk = wave & 1, wq = wave >> 1;

  __shared__ unsigned w2[8][132];            // packed half2 {w[q,2hp], w[q,2hp+1]}

  const int qrow0 = b * 4096 + qt * 128;
  const int krow0 = b * 4096 + kt * 128;

  // stage w tile: 128 rows x 16 heads fp32 -> half2 pairs
  {
    const float4* ws = (const float4*)(wf + (int64_t)qrow0 * 16);
#pragma unroll
    for (int r = 0; r < 2; ++r) {
      int f = tid * 2 + r;                   // 0..511 float4s
      float4 v = ws[f];
      int row = f >> 2, hb = (f & 3) * 4;    // heads hb..hb+3 (hb in {0,4,8,12})
      f16x2 p01, p23;
      p01.x = (__fp16)v.x; p01.y = (__fp16)v.y;
      p23.x = (__fp16)v.z; p23.y = (__fp16)v.w;
      w2[(hb >> 1) + 0][row] = h2_to_u32(p01);
      w2[(hb >> 1) + 1][row] = h2_to_u32(p23);
    }
  }

  // K fragments: shared across all 16 heads, kept in registers
  bf16x8 ka[4];
#pragma unroll
  for (int i = 0; i < 4; ++i) {
    int kk = krow0 + wk * 64 + i * 16 + l15;
    ka[i] = *(const bf16x8*)&qkwb[(int64_t)kk * NPAD + KCOL + quad * 8];
  }

  const unsigned short* qbase =
      qkwb + (int64_t)(qrow0 + wq * 64 + l15) * NPAD + quad * 8;

  f32x4 acc[4][4] = {};
  __syncthreads();

  const f16x2 hz = u32_to_h2(0u);
  const f32x4 z = {0.f, 0.f, 0.f, 0.f};

#pragma unroll
  for (int hp = 0; hp < 8; ++hp) {
    // loop-local q fragments for heads 2hp, 2hp+1 (static indices only)
    bf16x8 q0[4], q1[4];
#pragma unroll
    for (int j = 0; j < 4; ++j) {
      q0[j] = *(const bf16x8*)&qbase[(int64_t)j * 16 * NPAD + (2 * hp) * 32];
      q1[j] = *(const bf16x8*)&qbase[(int64_t)j * 16 * NPAD + (2 * hp + 1) * 32];
    }
    f16x2 wv[4];
#pragma unroll
    for (int j = 0; j < 4; ++j)
      wv[j] = u32_to_h2(w2[hp][wq * 64 + j * 16 + l15]);

#pragma unroll
    for (int i = 0; i < 4; ++i)
#pragma unroll
      for (int j = 0; j < 4; ++j) {
        f32x4 t0 = __builtin_amdgcn_mfma_f32_16x16x32_bf16(ka[i], q0[j], z, 0, 0, 0);
        f32x4 t1 = __builtin_amdgcn_mfma_f32_16x16x32_bf16(ka[i], q1[j], z, 0, 0, 0);
#pragma unroll
        for (int r = 0; r < 4; ++r) {
          f16x2 p = __builtin_amdgcn_cvt_pkrtz(t0[r], t1[r]);   // {s_h0, s_h1} f16
          p = __builtin_elementwise_max(p, hz);                  // relu both halves
          acc[i][j][r] = __builtin_amdgcn_fdot2(p, wv[j], acc[i][j][r], false);
        }
      }
  }

  // store: per (i,j) one dwordx4 along k
#pragma unroll
  for (int i = 0; i < 4; ++i)
#pragma unroll
    for (int j = 0; j < 4; ++j) {
      int q = qt * 128 + wq * 64 + j * 16 + l15;
      int k = kt * 128 + wk * 64 + i * 16 + quad * 4;
      float4 v = make_float4(acc[i][j][0], acc[i][j][1], acc[i][j][2], acc[i][j][3]);
      *(float4*)&out[((int64_t)b * 4096 + q) * 4096 + k] = v;
    }
}

extern "C" void kernel_launch(void* const* d_in, const int* in_sizes, int n_in,
                              void* d_out, int out_size, void* d_ws, size_t ws_size,
                              hipStream_t stream) {
  const float* x  = (const float*)d_in[0];
  const float* Wq = (const float*)d_in[1];
  const float* Wk = (const float*)d_in[2];
  const float* Ww = (const float*)d_in[3];
  float* out = (float*)d_out;

  char* ws = (char*)d_ws;
  unsigned short* xb   = (unsigned short*)ws;                 // 8192x2048 bf16 = 33,554,432 B
  unsigned short* Wp   = (unsigned short*)(ws + 33554432);    // 640x2048 bf16  =  2,621,440 B
  unsigned short* qkwb = (unsigned short*)(ws + 36175872);    // 8192x640 bf16  = 10,485,760 B
  float*          wf   = (float*)(ws + 46661632);             // 8192x16 fp32   =    524,288 B

  pack_kernel<<<17664, 256, 0, stream>>>(x, Wq, Wk, Ww, xb, Wp);
  gemm_proj<<<dim3(5, 64), 256, 0, stream>>>(xb, Wp, qkwb, wf);
  scores_kernel<<<dim3(32, 32, 2), 256, 0, stream>>>(qkwb, wf, out);
}

// Round 6
// 284.913 us; speedup vs baseline: 4.3603x; 1.0922x over previous
//
#include <hip/hip_runtime.h>
#include <hip/hip_bf16.h>
#include <stdint.h>

// LightningIndexer: importance[b,q,k] = sum_h w[b,q,h] * relu( qh[b,q,:] . kv[b,k,:] )
// B=2, T=4096, C=2048, H=16, D=32.
// Pipeline: (1) cast x + pack W -> bf16, (2) MFMA GEMM projections (64x128 tiles,
// 640 blocks), (3) fused score kernel. Intermediates are HEAD-MAJOR
// (qh[16][8192][32], kh[8192][32]) so scores' fragment loads are direct,
// perfectly-coalesced 1KiB-per-wave global reads (no LDS staging needed).
// Structure is the verified round-3 kernel; only address formulas changed.

typedef __attribute__((ext_vector_type(8))) short bf16x8;
typedef __attribute__((ext_vector_type(4))) float f32x4;
typedef __attribute__((ext_vector_type(2))) __fp16 f16x2;   // clang builtin half2 type

__device__ __forceinline__ unsigned short f2bf(float f) {
  union { float f; unsigned u; } c; c.f = f;
  unsigned u = c.u;
  u += 0x7FFFu + ((u >> 16) & 1u);   // round-to-nearest-even
  return (unsigned short)(u >> 16);
}

__device__ __forceinline__ f16x2 u32_to_h2(unsigned u) {
  union { unsigned u; f16x2 h; } c; c.u = u; return c.h;
}
__device__ __forceinline__ unsigned h2_to_u32(f16x2 h) {
  union { unsigned u; f16x2 h; } c; c.h = h; return c.u;
}

__device__ __forceinline__ void async_copy16(void* lds, const void* g) {
  __builtin_amdgcn_global_load_lds(
      (const __attribute__((address_space(1))) unsigned*)g,
      (__attribute__((address_space(3))) unsigned*)lds, 16, 0, 0);
}

// ---------------- kernel 1: cast x to bf16, pack Wq/Wk/Ww (+zero pad) ----------------
__global__ __launch_bounds__(256) void pack_kernel(
    const float* __restrict__ x, const float* __restrict__ Wq,
    const float* __restrict__ Wk, const float* __restrict__ Ww,
    unsigned short* __restrict__ xb, unsigned short* __restrict__ Wp) {
  const int64_t NX4 = 16777216 / 4;          // x float4 count
  int64_t i = (int64_t)blockIdx.x * 256 + threadIdx.x;
  if (i < NX4) {
    float4 v = ((const float4*)x)[i];
    ushort4 o;
    o.x = f2bf(v.x); o.y = f2bf(v.y); o.z = f2bf(v.z); o.w = f2bf(v.w);
    ((ushort4*)xb)[i] = o;
  } else {
    int p = (int)(i - NX4);                  // 0 .. 640*2048/4-1 = 327679
    int row = p >> 9;                        // 512 float4 per 2048-col row
    int col = (p & 511) << 2;
    float4 v = make_float4(0.f, 0.f, 0.f, 0.f);
    if (row < 512)      v = *(const float4*)(Wq + (int64_t)row * 2048 + col);
    else if (row < 544) v = *(const float4*)(Wk + (int64_t)(row - 512) * 2048 + col);
    else if (row < 560) v = *(const float4*)(Ww + (int64_t)(row - 544) * 2048 + col);
    ushort4 o;
    o.x = f2bf(v.x); o.y = f2bf(v.y); o.z = f2bf(v.z); o.w = f2bf(v.w);
    ((ushort4*)Wp)[p] = o;
  }
}

// ---------------- kernel 2: projections, 64x128 (m x n) tiles, 640 blocks ----------------
// grid (5, 128): n-tile 128 (640 cols), m-tile 64 (8192 rows). 256 threads,
// waves 1x4 in n: each wave computes 64x32. Single-buffer LDS, 2 barriers/k-step
// (the verified round-0/3 loop structure with substituted constants).
__global__ __launch_bounds__(256) void gemm_proj(
    const unsigned short* __restrict__ xb, const unsigned short* __restrict__ Wp,
    unsigned short* __restrict__ qh, unsigned short* __restrict__ kh,
    float* __restrict__ wf) {
  __shared__ short lds_a[64 * 32];           // 4 KB
  __shared__ short lds_b[128 * 32];          // 8 KB
  const int tid = threadIdx.x;
  const int lane = tid & 63;
  const int l15 = lane & 15, quad = lane >> 4;
  const int wave = tid >> 6;
  const int wn = wave;                       // 0..3
  const int m0 = blockIdx.y * 64, n0 = blockIdx.x * 128;

  const int c0 = tid, c1 = tid + 256;        // B: 512 chunks; A: 256 chunks
  const unsigned short* ga  = xb + (int64_t)(m0 + (tid >> 2)) * 2048 + (tid & 3) * 8;
  const unsigned short* gb0 = Wp + (int64_t)(n0 + (c0 >> 2)) * 2048 + (c0 & 3) * 8;
  const unsigned short* gb1 = Wp + (int64_t)(n0 + (c1 >> 2)) * 2048 + (c1 & 3) * 8;

  f32x4 acc[4][2] = {};

  for (int kt = 0; kt < 64; ++kt) {
    const int ko = kt * 32;
    async_copy16(&lds_a[tid * 8], ga + ko);
    async_copy16(&lds_b[c0 * 8], gb0 + ko);
    async_copy16(&lds_b[c1 * 8], gb1 + ko);
    __syncthreads();
    bf16x8 af[4], bfr[2];
#pragma unroll
    for (int i = 0; i < 4; ++i)
      af[i] = *(const bf16x8*)&lds_a[(i * 16 + l15) * 32 + quad * 8];
#pragma unroll
    for (int j = 0; j < 2; ++j)
      bfr[j] = *(const bf16x8*)&lds_b[(wn * 32 + j * 16 + l15) * 32 + quad * 8];
#pragma unroll
    for (int i = 0; i < 4; ++i)
#pragma unroll
      for (int j = 0; j < 2; ++j)
        acc[i][j] = __builtin_amdgcn_mfma_f32_16x16x32_bf16(af[i], bfr[j], acc[i][j], 0, 0, 0);
    __syncthreads();
  }

#pragma unroll
  for (int i = 0; i < 4; ++i)
#pragma unroll
    for (int j = 0; j < 2; ++j)
#pragma unroll
      for (int r = 0; r < 4; ++r) {
        int m = m0 + i * 16 + quad * 4 + r;
        int n = n0 + wn * 32 + j * 16 + l15;
        float v = acc[i][j][r];
        if (n < 512)      qh[((int64_t)(n >> 5) * 8192 + m) * 32 + (n & 31)] = f2bf(v);
        else if (n < 544) kh[(int64_t)m * 32 + (n - 512)] = f2bf(v);
        else if (n < 560) wf[m * 16 + (n - 544)] = v;   // w kept fp32
      }
}

// ---------------- kernel 3: fused scores ----------------
// Block: 128 k x 128 q tile (verified round-3 structure). Fragment loads go
// directly to head-major qh/kh: within a wave, (l15, quad) lanes cover one
// contiguous 1 KiB block -> perfectly coalesced, one cache line set per load.
// Epilogue: cvt_pkrtz + pk_max + fdot2 = 1.5 VALU ops per element-head.
__global__ __launch_bounds__(256) void scores_kernel(
    const unsigned short* __restrict__ qh, const unsigned short* __restrict__ kh,
    const float* __restrict__ wf, float* __restrict__ out) {
  const int kt = blockIdx.x, qt = blockIdx.y, b = blockIdx.z;
  const int tid = threadIdx.x;
  const int lane = tid & 63;
  const int l15 = lane & 15, quad = lane >> 4;
  const int wave = tid >> 6;
  const int wk = wave & 1, wq = wave >> 1;

  __shared__ unsigned w2[8][132];            // packed half2 {w[q,2hp], w[q,2hp+1]}

  const int qrow0 = b * 4096 + qt * 128;
  const int krow0 = b * 4096 + kt * 128;

  // stage w tile: 128 rows x 16 heads fp32 -> half2 pairs (contiguous reads)
  {
    const float4* ws = (const float4*)(wf + (int64_t)qrow0 * 16);
#pragma unroll
    for (int r = 0; r < 2; ++r) {
      int f = tid * 2 + r;                   // 0..511 float4s
      float4 v = ws[f];
      int row = f >> 2, hb = (f & 3) * 4;    // heads hb..hb+3
      f16x2 p01, p23;
      p01.x = (__fp16)v.x; p01.y = (__fp16)v.y;
      p23.x = (__fp16)v.z; p23.y = (__fp16)v.w;
      w2[(hb >> 1) + 0][row] = h2_to_u32(p01);
      w2[(hb >> 1) + 1][row] = h2_to_u32(p23);
    }
  }

  // K fragments: shared across all heads, registers for whole kernel.
  // kh row = krow0 + wk*64 + i*16 + l15 (64 B rows), col quad*8 -> coalesced.
  bf16x8 ka[4];
#pragma unroll
  for (int i = 0; i < 4; ++i) {
    int kk = krow0 + wk * 64 + i * 16 + l15;
    ka[i] = *(const bf16x8*)&kh[(int64_t)kk * 32 + quad * 8];
  }

  // q base for this thread: head h, row offset j*16 -> + h*8192*32 + j*512
  const unsigned short* qbase =
      qh + (int64_t)(qrow0 + wq * 64 + l15) * 32 + quad * 8;

  f32x4 acc[4][4] = {};
  __syncthreads();

  const f16x2 hz = u32_to_h2(0u);
  const f32x4 z = {0.f, 0.f, 0.f, 0.f};

#pragma unroll
  for (int hp = 0; hp < 8; ++hp) {
    // loop-local q fragments (static indices only — no cross-iteration arrays)
    bf16x8 q0[4], q1[4];
#pragma unroll
    for (int j = 0; j < 4; ++j) {
      q0[j] = *(const bf16x8*)&qbase[(int64_t)(2 * hp) * 262144 + j * 512];
      q1[j] = *(const bf16x8*)&qbase[(int64_t)(2 * hp + 1) * 262144 + j * 512];
    }
    f16x2 wv[4];
#pragma unroll
    for (int j = 0; j < 4; ++j)
      wv[j] = u32_to_h2(w2[hp][wq * 64 + j * 16 + l15]);

#pragma unroll
    for (int i = 0; i < 4; ++i)
#pragma unroll
      for (int j = 0; j < 4; ++j) {
        f32x4 t0 = __builtin_amdgcn_mfma_f32_16x16x32_bf16(ka[i], q0[j], z, 0, 0, 0);
        f32x4 t1 = __builtin_amdgcn_mfma_f32_16x16x32_bf16(ka[i], q1[j], z, 0, 0, 0);
#pragma unroll
        for (int r = 0; r < 4; ++r) {
          f16x2 p = __builtin_amdgcn_cvt_pkrtz(t0[r], t1[r]);   // {s_h0, s_h1} f16
          p = __builtin_elementwise_max(p, hz);                  // relu both halves
          acc[i][j][r] = __builtin_amdgcn_fdot2(p, wv[j], acc[i][j][r], false);
        }
      }
  }

  // store: per (i,j) one dwordx4 along k
#pragma unroll
  for (int i = 0; i < 4; ++i)
#pragma unroll
    for (int j = 0; j < 4; ++j) {
      int q = qt * 128 + wq * 64 + j * 16 + l15;
      int k = kt * 128 + wk * 64 + i * 16 + quad * 4;
      float4 v = make_float4(acc[i][j][0], acc[i][j][1], acc[i][j][2], acc[i][j][3]);
      *(float4*)&out[((int64_t)b * 4096 + q) * 4096 + k] = v;
    }
}

extern "C" void kernel_launch(void* const* d_in, const int* in_sizes, int n_in,
                              void* d_out, int out_size, void* d_ws, size_t ws_size,
                              hipStream_t stream) {
  const float* x  = (const float*)d_in[0];
  const float* Wq = (const float*)d_in[1];
  const float* Wk = (const float*)d_in[2];
  const float* Ww = (const float*)d_in[3];
  float* out = (float*)d_out;

  char* ws = (char*)d_ws;
  unsigned short* xb = (unsigned short*)ws;                 // 8192x2048 bf16 = 33,554,432 B
  unsigned short* Wp = (unsigned short*)(ws + 33554432);    // 640x2048 bf16  =  2,621,440 B
  unsigned short* qh = (unsigned short*)(ws + 36175872);    // 16x8192x32 bf16 = 8,388,608 B
  unsigned short* kh = (unsigned short*)(ws + 44564480);    // 8192x32 bf16   =    524,288 B
  float*          wf = (float*)(ws + 45088768);             // 8192x16 fp32   =    524,288 B

  pack_kernel<<<17664, 256, 0, stream>>>(x, Wq, Wk, Ww, xb, Wp);
  gemm_proj<<<dim3(5, 128), 256, 0, stream>>>(xb, Wp, qh, kh, wf);
  scores_kernel<<<dim3(32, 32, 2), 256, 0, stream>>>(qh, kh, wf, out);
}